// Round 5
// baseline (247.699 us; speedup 1.0000x reference)
//
#include <hip/hip_runtime.h>

#define NETS 32
#define BATCH 4096
#define D0 256
#define D1 512
#define D2 512
#define D3 128
#define MT 64            // batch rows per block
#define LDA (D0 + 8)     // 264 halves -> 528 B row stride
#define LDH (D1 + 8)     // 520 halves -> 1040 B row stride

using half8 = __attribute__((ext_vector_type(8))) _Float16;
using half4 = __attribute__((ext_vector_type(4))) _Float16;
using f32x4 = __attribute__((ext_vector_type(4))) float;

#define W1_N (NETS * D1 * D0)   // 4,194,304
#define W2_N (NETS * D2 * D1)   // 8,388,608
#define W3_N (NETS * D3 * D2)   // 2,097,152

// ---------------- fp32 -> fp16 cast + fragment swizzle ----------------
// Swizzled layout: fragment f = ((net*4 + w)*NF + kk*NI + ni), 512 halves each;
// lane l of a wave owns halves [l*8, l*8+8) = W[net][nbase+ni*16+(l&15)][kk*32+(l>>4)*8 ..+8).
// Each cvt thread reads ONE 64-B cacheline (16 fp32) and emits two half8 slices
// (lanes quad q and q+1 share a 16-half run of the same row).
template<int N, int K, int NI, int NWCH>
__device__ __forceinline__ void cvt_one(const float* __restrict__ W, _Float16* __restrict__ Wh, int u) {
    constexpr int NF = (K / 32) * NI;
    const int p = u & 31;
    const int f = u >> 5;
    const int fn = f % NF;
    const int netw = f / NF;
    const int kk = fn / NI, ni = fn % NI;
    const int net = netw >> 2, w = netw & 3;
    const int r = p & 15;
    const int kh = (p >> 4) * 16;          // 0 or 16
    const int n = w * NWCH + ni * 16 + r;
    const float* src = W + (size_t)net * N * K + (size_t)n * K + kk * 32 + kh;
    float4 v0 = *reinterpret_cast<const float4*>(src);
    float4 v1 = *reinterpret_cast<const float4*>(src + 4);
    float4 v2 = *reinterpret_cast<const float4*>(src + 8);
    float4 v3 = *reinterpret_cast<const float4*>(src + 12);
    half8 o0, o1;
    o0[0] = (_Float16)v0.x; o0[1] = (_Float16)v0.y; o0[2] = (_Float16)v0.z; o0[3] = (_Float16)v0.w;
    o0[4] = (_Float16)v1.x; o0[5] = (_Float16)v1.y; o0[6] = (_Float16)v1.z; o0[7] = (_Float16)v1.w;
    o1[0] = (_Float16)v2.x; o1[1] = (_Float16)v2.y; o1[2] = (_Float16)v2.z; o1[3] = (_Float16)v2.w;
    o1[4] = (_Float16)v3.x; o1[5] = (_Float16)v3.y; o1[6] = (_Float16)v3.z; o1[7] = (_Float16)v3.w;
    const int l1 = (kh >> 3) * 16 + r;     // quad (kh/8), lane within frag
    _Float16* dst = Wh + (size_t)f * 512 + l1 * 8;
    *reinterpret_cast<half8*>(dst) = o0;
    *reinterpret_cast<half8*>(dst + 128) = o1;   // lane l1+16 (next quad)
}

__global__ void cvt_weights(const float* __restrict__ W1, const float* __restrict__ W2,
                            const float* __restrict__ W3,
                            _Float16* __restrict__ W1h, _Float16* __restrict__ W2h,
                            _Float16* __restrict__ W3h) {
    const int i = blockIdx.x * blockDim.x + threadIdx.x;
    constexpr int T1 = W1_N / 16, T2 = W2_N / 16;     // threads per layer
    if (i < T1)            cvt_one<D1, D0, 8, 128>(W1, W1h, i);
    else if (i < T1 + T2)  cvt_one<D2, D1, 8, 128>(W2, W2h, i - T1);
    else                   cvt_one<D3, D2, 2,  32>(W3, W3h, i - T1 - T2);
}

// ---------------- kk-granular software-pipelined layer ----------------
// B fragments stream coalesced (1-KB/wave) from global; prefetch the full
// fragment set of kk+D while computing kk (rolling register buffer).
template<int K, int NI, int MI, int D>
__device__ __forceinline__ void layer_mfma(const _Float16* As, int lda,
                                           const _Float16* __restrict__ wl,
                                           int lane16, int quad,
                                           f32x4 (&acc)[MI][NI]) {
    constexpr int NKK = K / 32;
    half8 b[D + 1][NI];
#pragma unroll
    for (int d = 0; d < D; ++d)
#pragma unroll
        for (int ni = 0; ni < NI; ++ni)
            b[d][ni] = *reinterpret_cast<const half8*>(wl + (size_t)(d * NI + ni) * 512);
#pragma unroll
    for (int kk = 0; kk < NKK; ++kk) {
        if (kk + D < NKK) {
            const int slot = (kk + D) % (D + 1);
#pragma unroll
            for (int ni = 0; ni < NI; ++ni)
                b[slot][ni] = *reinterpret_cast<const half8*>(
                    wl + (size_t)((kk + D) * NI + ni) * 512);
        }
        half8 a[MI];
#pragma unroll
        for (int mi = 0; mi < MI; ++mi)
            a[mi] = *reinterpret_cast<const half8*>(
                As + (mi * 16 + lane16) * lda + kk * 32 + quad * 8);
        const int cs = kk % (D + 1);
#pragma unroll
        for (int ni = 0; ni < NI; ++ni)
#pragma unroll
            for (int mi = 0; mi < MI; ++mi)
                acc[mi][ni] = __builtin_amdgcn_mfma_f32_16x16x32_f16(a[mi], b[cs][ni], acc[mi][ni], 0, 0, 0);
    }
}

template<int MI, int NI>
__device__ __forceinline__ void store_act(f32x4 (&acc)[MI][NI], const float* __restrict__ bias,
                                          _Float16* dst, int ldd, int n_base,
                                          int lane16, int quad) {
#pragma unroll
    for (int ni = 0; ni < NI; ++ni) {
        float bv = bias[n_base + ni * 16 + lane16];
        int col = n_base + ni * 16 + lane16;
#pragma unroll
        for (int mi = 0; mi < MI; ++mi) {
#pragma unroll
            for (int r = 0; r < 4; ++r) {
                float v = acc[mi][ni][r] + bv;
                v = fmaxf(v, 0.0f);                        // relu
                int row = mi * 16 + quad * 4 + r;
                dst[row * ldd + col] = (_Float16)v;
            }
        }
    }
}

// ---------------- fused 3-layer MLP, single in-place LDS buffer ----------------
__global__ __launch_bounds__(256, 2) void mlp_fused(
    const float* __restrict__ X,
    const _Float16* __restrict__ W1h, const float* __restrict__ b1,
    const _Float16* __restrict__ W2h, const float* __restrict__ b2,
    const _Float16* __restrict__ W3h, const float* __restrict__ b3,
    float* __restrict__ out) {
    __shared__ __align__(16) _Float16 buf[MT * LDH];   // X (LDA layout) -> H1 -> H2 (LDH)

    const int tid = threadIdx.x;
    const int w = tid >> 6;
    const int l = tid & 63;
    const int lane16 = l & 15;
    const int quad = l >> 4;

    // XCD-locality: dispatch round-robins blockIdx over 8 XCDs -> 4 nets/XCD.
    const int bb = blockIdx.x;            // 0..2047
    const int xcd = bb & 7;
    const int s = bb >> 3;                // 0..255
    const int net = xcd * 4 + (s >> 6);   // 0..31
    const int mt = s & 63;                // 0..63
    const int m0 = mt * MT;

    // ---- stage X tile [MT][D0] fp32 -> fp16 into buf (LDA layout) ----
    {
        const float* xsrc = X + (size_t)m0 * D0;
#pragma unroll
        for (int it = 0; it < 16; ++it) {
            int chunk = it * 256 + tid;   // 0..4095; 64 float4 per row
            int row = chunk >> 6;
            int c4 = chunk & 63;
            float4 v = *reinterpret_cast<const float4*>(xsrc + row * D0 + c4 * 4);
            half4 o;
            o[0] = (_Float16)v.x; o[1] = (_Float16)v.y;
            o[2] = (_Float16)v.z; o[3] = (_Float16)v.w;
            *reinterpret_cast<half4*>(&buf[row * LDA + c4 * 4]) = o;
        }
    }
    __syncthreads();

    // ---- layer 1: H1 = relu(X @ W1^T + b1), K=256, N=512 (wave owns 128 cols) ----
    {
        f32x4 acc[4][8] = {};
        const _Float16* wl = W1h + ((size_t)(net * 4 + w) * 64) * 512 + l * 8;
        layer_mfma<D0, 8, 4, 1>(buf, LDA, wl, lane16, quad, acc);
        __syncthreads();                               // all X reads done
        store_act<4, 8>(acc, b1 + net * D1, buf, LDH, w * 128, lane16, quad);
    }
    __syncthreads();

    // ---- layer 2: H2 = relu(H1 @ W2^T + b2), K=512, N=512 ----
    {
        f32x4 acc[4][8] = {};
        const _Float16* wl = W2h + ((size_t)(net * 4 + w) * 128) * 512 + l * 8;
        layer_mfma<D1, 8, 4, 1>(buf, LDH, wl, lane16, quad, acc);
        __syncthreads();                               // all H1 reads done
        store_act<4, 8>(acc, b2 + net * D2, buf, LDH, w * 128, lane16, quad);
    }
    __syncthreads();

    // ---- layer 3: out = H2 @ W3^T + b3, K=512, N=128 (wave owns 32 cols) ----
    {
        f32x4 acc[4][2] = {};
        const _Float16* wl = W3h + ((size_t)(net * 4 + w) * 32) * 512 + l * 8;
        layer_mfma<D2, 2, 4, 3>(buf, LDH, wl, lane16, quad, acc);
        const int n_base = w * 32;
#pragma unroll
        for (int ni = 0; ni < 2; ++ni) {
            float bv = b3[net * D3 + n_base + ni * 16 + lane16];
            int col = net * D3 + n_base + ni * 16 + lane16;
#pragma unroll
            for (int mi = 0; mi < 4; ++mi) {
#pragma unroll
                for (int r = 0; r < 4; ++r) {
                    int row = m0 + mi * 16 + quad * 4 + r;
                    out[(size_t)row * (NETS * D3) + col] = acc[mi][ni][r] + bv;
                }
            }
        }
    }
}

extern "C" void kernel_launch(void* const* d_in, const int* in_sizes, int n_in,
                              void* d_out, int out_size, void* d_ws, size_t ws_size,
                              hipStream_t stream) {
    const float* x  = (const float*)d_in[0];
    const float* W1 = (const float*)d_in[1];
    const float* b1 = (const float*)d_in[2];
    const float* W2 = (const float*)d_in[3];
    const float* b2 = (const float*)d_in[4];
    const float* W3 = (const float*)d_in[5];
    const float* b3 = (const float*)d_in[6];
    float* out = (float*)d_out;

    // ws layout (fp16, swizzled): W1h | W2h | W3h  = ~29.4 MB total
    _Float16* W1h = (_Float16*)d_ws;
    _Float16* W2h = W1h + (size_t)W1_N;
    _Float16* W3h = W2h + (size_t)W2_N;

    const int totalT = (W1_N + W2_N + W3_N) / 16;      // 917,504 threads
    cvt_weights<<<totalT / 256, 256, 0, stream>>>(W1, W2, W3, W1h, W2h, W3h);

    mlp_fused<<<NETS * (BATCH / MT), 256, 0, stream>>>(x, W1h, b1, W2h, b2, W3h, b3, out);
}

// Round 6
// 244.667 us; speedup vs baseline: 1.0124x; 1.0124x over previous
//
#include <hip/hip_runtime.h>

#define NETS 32
#define BATCH 4096
#define D0 256
#define D1 512
#define D2 512
#define D3 128
#define MT 64            // batch rows per block
#define LDA (D0 + 8)     // 264 halves -> 4-bank rotation per row
#define LDH (D1 + 8)     // 520 halves

using half8  = __attribute__((ext_vector_type(8))) _Float16;
using f32x16 = __attribute__((ext_vector_type(16))) float;

#define W1_N (NETS * D1 * D0)   // 4,194,304
#define W2_N (NETS * D2 * D1)   // 8,388,608
#define W3_N (NETS * D3 * D2)   // 2,097,152
#define X_N  (BATCH * D0)       // 1,048,576

// ---------------- prologue: fp32 -> fp16 cast + fragment swizzle ----------------
// 32x32x16 B-fragment: frag f = ((net*4+w)*NKK + kk)*NI + ni, 512 halves.
// Lane l owns halves [l*8,l*8+8) = W[net][w*WCH + ni*32 + (l&31)][kk*16 + (l>>5)*8 + j].
// Each cvt thread reads ONE 64-B line (16 fp32 of one row) = the two k-octets
// of one fragment column -> two half8 slices at +0 and +256.
template<int N, int K, int NI, int WSH>
__device__ __forceinline__ void cvt_w(const float* __restrict__ W, _Float16* __restrict__ Wh, int u) {
    constexpr int NKK = K / 16;
    const int t  = u % NKK;
    const int rg = u / NKK;
    const int n   = rg % N;
    const int net = rg / N;
    const int w  = n >> WSH;
    const int ni = (n >> 5) & (NI - 1);
    const int m  = n & 31;
    const float* src = W + (size_t)net * N * K + (size_t)n * K + t * 16;
    float4 v0 = *reinterpret_cast<const float4*>(src);
    float4 v1 = *reinterpret_cast<const float4*>(src + 4);
    float4 v2 = *reinterpret_cast<const float4*>(src + 8);
    float4 v3 = *reinterpret_cast<const float4*>(src + 12);
    half8 o0, o1;
    o0[0] = (_Float16)v0.x; o0[1] = (_Float16)v0.y; o0[2] = (_Float16)v0.z; o0[3] = (_Float16)v0.w;
    o0[4] = (_Float16)v1.x; o0[5] = (_Float16)v1.y; o0[6] = (_Float16)v1.z; o0[7] = (_Float16)v1.w;
    o1[0] = (_Float16)v2.x; o1[1] = (_Float16)v2.y; o1[2] = (_Float16)v2.z; o1[3] = (_Float16)v2.w;
    o1[4] = (_Float16)v3.x; o1[5] = (_Float16)v3.y; o1[6] = (_Float16)v3.z; o1[7] = (_Float16)v3.w;
    const int f = ((net * 4 + w) * NKK + t) * NI + ni;
    _Float16* dst = Wh + (size_t)f * 512 + m * 8;
    *reinterpret_cast<half8*>(dst)       = o0;   // lane m      (k-octet 0)
    *reinterpret_cast<half8*>(dst + 256) = o1;   // lane m + 32 (k-octet 1)
}

__global__ void cvt_all(const float* __restrict__ x,
                        const float* __restrict__ W1, const float* __restrict__ W2,
                        const float* __restrict__ W3,
                        _Float16* __restrict__ Xh,
                        _Float16* __restrict__ W1h, _Float16* __restrict__ W2h,
                        _Float16* __restrict__ W3h) {
    const int i = blockIdx.x * blockDim.x + threadIdx.x;
    constexpr int TX = X_N / 16, T1 = W1_N / 16, T2 = W2_N / 16;
    if (i < TX) {
        // X: plain row-major fp16 copy, one 64-B line per thread
        const float* src = x + (size_t)i * 16;
        float4 v0 = *reinterpret_cast<const float4*>(src);
        float4 v1 = *reinterpret_cast<const float4*>(src + 4);
        float4 v2 = *reinterpret_cast<const float4*>(src + 8);
        float4 v3 = *reinterpret_cast<const float4*>(src + 12);
        half8 o0, o1;
        o0[0] = (_Float16)v0.x; o0[1] = (_Float16)v0.y; o0[2] = (_Float16)v0.z; o0[3] = (_Float16)v0.w;
        o0[4] = (_Float16)v1.x; o0[5] = (_Float16)v1.y; o0[6] = (_Float16)v1.z; o0[7] = (_Float16)v1.w;
        o1[0] = (_Float16)v2.x; o1[1] = (_Float16)v2.y; o1[2] = (_Float16)v2.z; o1[3] = (_Float16)v2.w;
        o1[4] = (_Float16)v3.x; o1[5] = (_Float16)v3.y; o1[6] = (_Float16)v3.z; o1[7] = (_Float16)v3.w;
        _Float16* dst = Xh + (size_t)i * 16;
        *reinterpret_cast<half8*>(dst)     = o0;
        *reinterpret_cast<half8*>(dst + 8) = o1;
    }
    else if (i < TX + T1)           cvt_w<D1, D0, 4, 7>(W1, W1h, i - TX);
    else if (i < TX + T1 + T2)      cvt_w<D2, D1, 4, 7>(W2, W2h, i - TX - T1);
    else                            cvt_w<D3, D2, 1, 5>(W3, W3h, i - TX - T1 - T2);
}

// ---------------- kk-granular pipelined layer, 32x32x16 MFMA ----------------
// B frags stream coalesced (1 KB/wave) from global, prefetched D kk-steps ahead
// in a rolling register buffer. A frags (two 32-row tiles) from LDS.
template<int K, int NI, int MI, int D>
__device__ __forceinline__ void layer32(const _Float16* As, int lda,
                                        const _Float16* __restrict__ wl,
                                        int lane_m, int oct,
                                        f32x16 (&acc)[MI][NI]) {
    constexpr int NKK = K / 16;
    half8 b[D + 1][NI];
#pragma unroll
    for (int d = 0; d < D; ++d)
#pragma unroll
        for (int ni = 0; ni < NI; ++ni)
            b[d][ni] = *reinterpret_cast<const half8*>(wl + (size_t)(d * NI + ni) * 512);
#pragma unroll
    for (int kk = 0; kk < NKK; ++kk) {
        if (kk + D < NKK) {
            const int slot = (kk + D) % (D + 1);
#pragma unroll
            for (int ni = 0; ni < NI; ++ni)
                b[slot][ni] = *reinterpret_cast<const half8*>(
                    wl + (size_t)((kk + D) * NI + ni) * 512);
        }
        half8 a[MI];
#pragma unroll
        for (int mi = 0; mi < MI; ++mi)
            a[mi] = *reinterpret_cast<const half8*>(
                As + (mi * 32 + lane_m) * lda + kk * 16 + oct * 8);
        const int cs = kk % (D + 1);
#pragma unroll
        for (int ni = 0; ni < NI; ++ni)
#pragma unroll
            for (int mi = 0; mi < MI; ++mi)
                acc[mi][ni] = __builtin_amdgcn_mfma_f32_32x32x16_f16(a[mi], b[cs][ni], acc[mi][ni], 0, 0, 0);
    }
}

// C/D 32x32 layout: col = n_base + ni*32 + lane_m; row = mi*32 + (r&3) + 8*(r>>2) + 4*oct
template<int MI, int NI>
__device__ __forceinline__ void store_act32(f32x16 (&acc)[MI][NI], const float* __restrict__ bias,
                                            _Float16* dst, int ldd, int n_base,
                                            int lane_m, int oct) {
#pragma unroll
    for (int ni = 0; ni < NI; ++ni) {
        const int col = n_base + ni * 32 + lane_m;
        float bv = bias[col];
#pragma unroll
        for (int mi = 0; mi < MI; ++mi) {
#pragma unroll
            for (int r = 0; r < 16; ++r) {
                float v = acc[mi][ni][r] + bv;
                v = fmaxf(v, 0.0f);                        // relu
                int row = mi * 32 + (r & 3) + 8 * (r >> 2) + 4 * oct;
                dst[row * ldd + col] = (_Float16)v;
            }
        }
    }
}

// ---------------- fused 3-layer MLP, single in-place LDS buffer ----------------
__global__ __launch_bounds__(256, 2) void mlp_fused(
    const _Float16* __restrict__ Xh,
    const _Float16* __restrict__ W1h, const float* __restrict__ b1,
    const _Float16* __restrict__ W2h, const float* __restrict__ b2,
    const _Float16* __restrict__ W3h, const float* __restrict__ b3,
    float* __restrict__ out) {
    __shared__ __align__(16) _Float16 buf[MT * LDH];   // X (LDA layout) -> H1 -> H2 (LDH)

    const int tid = threadIdx.x;
    const int w = tid >> 6;
    const int l = tid & 63;
    const int lane_m = l & 31;
    const int oct = l >> 5;

    // XCD-locality: dispatch round-robins blockIdx over 8 XCDs; sequence nets
    // over time so each XCD-L2 holds ~1 net's weights (~918 KB) at a time.
    const int bb = blockIdx.x;            // 0..2047
    const int xcd = bb & 7;
    const int s = bb >> 3;                // 0..255
    const int net = xcd * 4 + (s >> 6);   // 0..31
    const int mt = s & 63;                // 0..63
    const int m0 = mt * MT;

    // ---- stage X tile [MT][D0] fp16 into buf (LDA layout), 16-B copies ----
    {
        const _Float16* xsrc = Xh + (size_t)m0 * D0;
#pragma unroll
        for (int it = 0; it < 8; ++it) {
            int chunk = it * 256 + tid;   // 0..2047; 32 half8 per row
            int row = chunk >> 5;
            int c8 = chunk & 31;
            *reinterpret_cast<half8*>(&buf[row * LDA + c8 * 8]) =
                *reinterpret_cast<const half8*>(xsrc + row * D0 + c8 * 8);
        }
    }
    __syncthreads();

    // ---- layer 1: H1 = relu(X @ W1^T + b1), K=256, N=512 (wave owns 128 cols) ----
    {
        f32x16 acc[2][4] = {};
        const _Float16* wl = W1h + ((size_t)(net * 4 + w) * 64) * 512 + l * 8;
        layer32<D0, 4, 2, 2>(buf, LDA, wl, lane_m, oct, acc);
        __syncthreads();                               // all X reads done
        store_act32<2, 4>(acc, b1 + net * D1, buf, LDH, w * 128, lane_m, oct);
    }
    __syncthreads();

    // ---- layer 2: H2 = relu(H1 @ W2^T + b2), K=512, N=512 ----
    {
        f32x16 acc[2][4] = {};
        const _Float16* wl = W2h + ((size_t)(net * 4 + w) * 128) * 512 + l * 8;
        layer32<D1, 4, 2, 2>(buf, LDH, wl, lane_m, oct, acc);
        __syncthreads();                               // all H1 reads done
        store_act32<2, 4>(acc, b2 + net * D2, buf, LDH, w * 128, lane_m, oct);
    }
    __syncthreads();

    // ---- layer 3: out = H2 @ W3^T + b3, K=512, N=128 (wave owns 32 cols) ----
    {
        f32x16 acc[2][1] = {};
        const _Float16* wl = W3h + ((size_t)(net * 4 + w) * 32) * 512 + l * 8;
        layer32<D2, 1, 2, 8>(buf, LDH, wl, lane_m, oct, acc);
        const int col = net * D3 + w * 32 + lane_m;
        float bv = b3[net * D3 + w * 32 + lane_m];
#pragma unroll
        for (int mi = 0; mi < 2; ++mi) {
#pragma unroll
            for (int r = 0; r < 16; ++r) {
                int row = m0 + mi * 32 + (r & 3) + 8 * (r >> 2) + 4 * oct;
                out[(size_t)row * (NETS * D3) + col] = acc[mi][0][r] + bv;
            }
        }
    }
}

extern "C" void kernel_launch(void* const* d_in, const int* in_sizes, int n_in,
                              void* d_out, int out_size, void* d_ws, size_t ws_size,
                              hipStream_t stream) {
    const float* x  = (const float*)d_in[0];
    const float* W1 = (const float*)d_in[1];
    const float* b1 = (const float*)d_in[2];
    const float* W2 = (const float*)d_in[3];
    const float* b2 = (const float*)d_in[4];
    const float* W3 = (const float*)d_in[5];
    const float* b3 = (const float*)d_in[6];
    float* out = (float*)d_out;

    // ws layout (fp16): Xh | W1h | W2h | W3h  = ~31.5 MB total
    _Float16* Xh  = (_Float16*)d_ws;
    _Float16* W1h = Xh  + (size_t)X_N;
    _Float16* W2h = W1h + (size_t)W1_N;
    _Float16* W3h = W2h + (size_t)W2_N;

    const int totalT = (X_N + W1_N + W2_N + W3_N) / 16;    // 983,040 threads
    cvt_all<<<totalT / 256, 256, 0, stream>>>(x, W1, W2, W3, Xh, W1h, W2h, W3h);

    mlp_fused<<<NETS * (BATCH / MT), 256, 0, stream>>>(Xh, W1h, b1, W2h, b2, W3h, b3, out);
}